// Round 1
// baseline (1774.502 us; speedup 1.0000x reference)
//
#include <hip/hip_runtime.h>
#include <cstdint>

#define TOKS 4096
#define DIMD 2048
#define NE   16
#define HE   1408
#define HSH  2816

typedef unsigned short u16;
typedef __attribute__((ext_vector_type(8))) __bf16 bf16x8;
typedef __attribute__((ext_vector_type(4))) float  f32x4;

__device__ inline unsigned f2bf_pack(float a, float b) {
  unsigned ua = __builtin_bit_cast(unsigned, a);
  unsigned ub = __builtin_bit_cast(unsigned, b);
  ua = (ua + 0x7FFFu + ((ua >> 16) & 1u)) >> 16;
  ub = (ub + 0x7FFFu + ((ub >> 16) & 1u)) >> 16;
  return ua | (ub << 16);
}
__device__ inline u16 f2bf(float a) {
  unsigned ua = __builtin_bit_cast(unsigned, a);
  return (u16)((ua + 0x7FFFu + ((ua >> 16) & 1u)) >> 16);
}

// ---------------- gate: scores -> softmax -> top2 -> lists ----------------
__global__ __launch_bounds__(64)
void gate_kernel(const float* __restrict__ x, const float* __restrict__ gw,
                 float* __restrict__ probs, int* __restrict__ counts,
                 int* __restrict__ toklist, float* __restrict__ wtslist)
{
  const int t = blockIdx.x;
  const int l = threadIdx.x;
  const float* xr = x + (size_t)t * DIMD;
  float xv[32];
#pragma unroll
  for (int j = 0; j < 32; ++j) xv[j] = xr[j * 64 + l];

  float sc[16];
#pragma unroll
  for (int e = 0; e < 16; ++e) {
    const float* g = gw + (size_t)e * DIMD;
    float s = 0.f;
#pragma unroll
    for (int j = 0; j < 32; ++j) s += xv[j] * g[j * 64 + l];
#pragma unroll
    for (int o = 32; o > 0; o >>= 1) s += __shfl_down(s, o);
    sc[e] = s;  // valid on lane 0
  }
  if (l == 0) {
    float mx = sc[0];
#pragma unroll
    for (int e = 1; e < 16; ++e) mx = fmaxf(mx, sc[e]);
    float pe[16]; float sum = 0.f;
#pragma unroll
    for (int e = 0; e < 16; ++e) { pe[e] = __expf(sc[e] - mx); sum += pe[e]; }
    float inv = 1.f / sum;
    int b0 = -1, b1 = -1; float v0 = -1.f, v1 = -1.f;
#pragma unroll
    for (int e = 0; e < 16; ++e) {
      float p = pe[e] * inv;
      probs[t * 16 + e] = p;
      if (p > v0) { v1 = v0; b1 = b0; v0 = p; b0 = e; }
      else if (p > v1) { v1 = p; b1 = e; }
    }
    float wsum = v0 + v1 + 1e-9f;
    float w0 = v0 / wsum, w1 = v1 / wsum;
    int p0 = atomicAdd(&counts[b0], 1);
    toklist[b0 * TOKS + p0] = t; wtslist[b0 * TOKS + p0] = w0;
    int p1 = atomicAdd(&counts[b1], 1);
    toklist[b1 * TOKS + p1] = t; wtslist[b1 * TOKS + p1] = w1;
  }
}

// ------------- cleanup: offsets + aux loss -------------
__global__ __launch_bounds__(256)
void cleanup_kernel(const float* __restrict__ probs, const float* __restrict__ wtslist,
                    const int* __restrict__ counts, int* __restrict__ offs,
                    float* __restrict__ out_aux)
{
  const int tid = threadIdx.x;
  float imp[16], ld[16];
#pragma unroll
  for (int e = 0; e < 16; ++e) { imp[e] = 0.f; ld[e] = 0.f; }
  for (int t = tid; t < TOKS; t += 256) {
#pragma unroll
    for (int e = 0; e < 16; ++e) imp[e] += probs[t * 16 + e];
  }
  __shared__ int scnt[16];
  if (tid < 16) scnt[tid] = counts[tid];
  __syncthreads();
#pragma unroll
  for (int e = 0; e < 16; ++e) {
    int c = scnt[e];
    for (int p = tid; p < c; p += 256) ld[e] += wtslist[e * TOKS + p];
  }
  __shared__ float simp[16], sld[16];
  if (tid < 16) { simp[tid] = 0.f; sld[tid] = 0.f; }
  __syncthreads();
#pragma unroll
  for (int e = 0; e < 16; ++e) { atomicAdd(&simp[e], imp[e]); atomicAdd(&sld[e], ld[e]); }
  __syncthreads();
  if (tid == 0) {
    int off = 0;
    for (int e = 0; e < 16; ++e) { offs[e] = off; off += scnt[e]; }
    float tot = 0.f;
    for (int e = 0; e < 16; ++e) tot += sld[e];
    float aux = 0.f;
    for (int e = 0; e < 16; ++e) aux += (simp[e] / (float)TOKS) * (sld[e] / (tot + 1e-9f));
    *out_aux = 16.f * aux;
  }
}

// ------------- templated MFMA GEMM (C = A * B^T), 128x128 tile, BK=32 -------------
// MODE 0: A=x f32 [4096,2048], B=sw1,sw3 [2816,2048]; out U bf16 (silu(g1)*g3)
// MODE 1: A=U bf16 [4096,2816], B=sw2 [2048,2816];    out y f32 (store)
// MODE 2: A=x f32 gathered,     B=w1[e],w3[e];        out Act bf16 (silu*wt)
// MODE 3: A=Act bf16,           B=w2[e];              atomicAdd into y
template<int MODE>
__global__ __launch_bounds__(256)
void moe_gemm(const float* __restrict__ Af, const u16* __restrict__ Ab,
              const float* __restrict__ B1g, const float* __restrict__ B3g,
              u16* __restrict__ Obf, float* __restrict__ Of,
              const int* __restrict__ counts, const int* __restrict__ offs,
              const int* __restrict__ toklist, const float* __restrict__ wts)
{
  constexpr int KD = (MODE == 0) ? DIMD : (MODE == 1) ? HSH : (MODE == 2) ? DIMD : HE;
  constexpr int ND = (MODE == 0) ? HSH : (MODE == 1) ? DIMD : (MODE == 2) ? HE : DIMD;
  constexpr bool DUAL = (MODE == 0 || MODE == 2);
  constexpr int LDP = 40;  // padded bf16 row stride (32 data + 8 pad) -> no 4-way+ conflicts

  __shared__ u16 sA[128 * LDP];
  __shared__ u16 sB1[128 * LDP];
  __shared__ u16 sB3[DUAL ? 128 * LDP : 8];

  const int tid = threadIdx.x;
  const int lane = tid & 63;
  const int wave = tid >> 6;
  const int wm = wave >> 1, wn = wave & 1;
  const int mbase = blockIdx.y * 128;
  const int nbase = blockIdx.x * 128;

  int e = 0, cnt = 0;
  const int* tl = nullptr;
  long aoff = 0;
  const float* B1 = B1g;
  const float* B3 = B3g;
  if constexpr (MODE == 2) {
    e = blockIdx.z; cnt = counts[e];
    if (mbase >= cnt) return;
    tl = toklist + e * TOKS + mbase;
    B1 = B1g + (long)e * HE * DIMD;
    B3 = B3g + (long)e * HE * DIMD;
    aoff = offs[e];
  }
  if constexpr (MODE == 3) {
    e = blockIdx.z; cnt = counts[e];
    if (mbase >= cnt) return;
    tl = toklist + e * TOKS + mbase;
    B1 = B1g + (long)e * DIMD * HE;
    aoff = offs[e];
  }

  f32x4 acc1[4][4];
  f32x4 acc3[DUAL ? 4 : 1][DUAL ? 4 : 1];
#pragma unroll
  for (int i = 0; i < 4; ++i)
#pragma unroll
    for (int j = 0; j < 4; ++j) {
      acc1[i][j] = (f32x4){0.f, 0.f, 0.f, 0.f};
      if constexpr (DUAL) acc3[i][j] = (f32x4){0.f, 0.f, 0.f, 0.f};
    }

  int aoffs[4], boffs[4];
#pragma unroll
  for (int i = 0; i < 4; ++i) {
    aoffs[i] = (wm * 64 + i * 16 + (lane & 15)) * LDP + (lane >> 4) * 8;
    boffs[i] = (wn * 64 + i * 16 + (lane & 15)) * LDP + (lane >> 4) * 8;
  }

  for (int kb = 0; kb < KD; kb += 32) {
    // ---- stage tiles (fp32 -> bf16 convert, or bf16 copy) ----
#pragma unroll
    for (int p = 0; p < 4; ++p) {
      int idx = tid + p * 256;
      int row = idx >> 3;
      int c4 = (idx & 7) * 4;
      // A tile
      if constexpr (MODE == 0) {
        float4 v = *(const float4*)(Af + (size_t)(mbase + row) * KD + kb + c4);
        uint2 pk; pk.x = f2bf_pack(v.x, v.y); pk.y = f2bf_pack(v.z, v.w);
        *(uint2*)&sA[row * LDP + c4] = pk;
      } else if constexpr (MODE == 2) {
        int r = mbase + row;
        int tok = (r < cnt) ? tl[row] : 0;
        float4 v = *(const float4*)(Af + (size_t)tok * DIMD + kb + c4);
        uint2 pk; pk.x = f2bf_pack(v.x, v.y); pk.y = f2bf_pack(v.z, v.w);
        *(uint2*)&sA[row * LDP + c4] = pk;
      } else {
        long arow;
        if constexpr (MODE == 1) arow = mbase + row;
        else arow = aoff + ((mbase + row < cnt) ? (mbase + row) : 0);
        uint2 v = *(const uint2*)(Ab + arow * KD + kb + c4);
        *(uint2*)&sA[row * LDP + c4] = v;
      }
      // B1 tile
      {
        float4 v = *(const float4*)(B1 + (size_t)(nbase + row) * KD + kb + c4);
        uint2 pk; pk.x = f2bf_pack(v.x, v.y); pk.y = f2bf_pack(v.z, v.w);
        *(uint2*)&sB1[row * LDP + c4] = pk;
      }
      if constexpr (DUAL) {
        float4 v = *(const float4*)(B3 + (size_t)(nbase + row) * KD + kb + c4);
        uint2 pk; pk.x = f2bf_pack(v.x, v.y); pk.y = f2bf_pack(v.z, v.w);
        *(uint2*)&sB3[row * LDP + c4] = pk;
      }
    }
    __syncthreads();
    // ---- compute ----
    bf16x8 af[4], b1f[4];
#pragma unroll
    for (int i = 0; i < 4; ++i) af[i] = *(const bf16x8*)&sA[aoffs[i]];
#pragma unroll
    for (int i = 0; i < 4; ++i) b1f[i] = *(const bf16x8*)&sB1[boffs[i]];
#pragma unroll
    for (int mi = 0; mi < 4; ++mi)
#pragma unroll
      for (int ni = 0; ni < 4; ++ni)
        acc1[mi][ni] = __builtin_amdgcn_mfma_f32_16x16x32_bf16(af[mi], b1f[ni], acc1[mi][ni], 0, 0, 0);
    if constexpr (DUAL) {
      bf16x8 b3f[4];
#pragma unroll
      for (int i = 0; i < 4; ++i) b3f[i] = *(const bf16x8*)&sB3[boffs[i]];
#pragma unroll
      for (int mi = 0; mi < 4; ++mi)
#pragma unroll
        for (int ni = 0; ni < 4; ++ni)
          acc3[mi][ni] = __builtin_amdgcn_mfma_f32_16x16x32_bf16(af[mi], b3f[ni], acc3[mi][ni], 0, 0, 0);
    }
    __syncthreads();
  }

  // ---- epilogue ----
  const int lq4 = (lane >> 4) * 4;
  const int lc = lane & 15;
#pragma unroll
  for (int mi = 0; mi < 4; ++mi) {
#pragma unroll
    for (int ni = 0; ni < 4; ++ni) {
#pragma unroll
      for (int r = 0; r < 4; ++r) {
        int lrow = wm * 64 + mi * 16 + lq4 + r;
        int col = nbase + wn * 64 + ni * 16 + lc;
        float v1 = acc1[mi][ni][r];
        if constexpr (MODE == 0) {
          float v3 = acc3[mi][ni][r];
          float u = (v1 / (1.f + __expf(-v1))) * v3;
          Obf[(size_t)(mbase + lrow) * ND + col] = f2bf(u);
        } else if constexpr (MODE == 1) {
          Of[(size_t)(mbase + lrow) * ND + col] = v1;
        } else if constexpr (MODE == 2) {
          int grow = mbase + lrow;
          if (grow < cnt) {
            float v3 = acc3[mi][ni][r];
            float u = (v1 / (1.f + __expf(-v1))) * v3 * wts[e * TOKS + grow];
            Obf[(size_t)(aoff + grow) * ND + col] = f2bf(u);
          }
        } else {
          int grow = mbase + lrow;
          if (grow < cnt) {
            int tok = toklist[e * TOKS + grow];
            atomicAdd(&Of[(size_t)tok * DIMD + col], v1);
          }
        }
      }
    }
  }
}

extern "C" void kernel_launch(void* const* d_in, const int* in_sizes, int n_in,
                              void* d_out, int out_size, void* d_ws, size_t ws_size,
                              hipStream_t stream) {
  const float* x      = (const float*)d_in[0];
  const float* gate_w = (const float*)d_in[1];
  const float* w1     = (const float*)d_in[2];
  const float* w2     = (const float*)d_in[3];
  const float* w3     = (const float*)d_in[4];
  const float* sw1    = (const float*)d_in[5];
  const float* sw2    = (const float*)d_in[6];
  const float* sw3    = (const float*)d_in[7];
  float* out = (float*)d_out;

  char* ws = (char*)d_ws;
  int*   counts  = (int*)ws;                       // 16 ints
  int*   offsv   = (int*)(ws + 64);                // 16 ints
  int*   toklist = (int*)(ws + 256);               // 16*4096 ints
  float* wtslist = (float*)(ws + 262400);          // 16*4096 f32
  float* probs   = (float*)(ws + 524544);          // 4096*16 f32
  u16*   U       = (u16*)(ws + 1048576);           // 4096*2816 bf16  (~23MB)
  u16*   Act     = (u16*)(ws + 24117248);          // 8192*1408 bf16  (~23MB)

  hipMemsetAsync(counts, 0, 64, stream);
  gate_kernel<<<TOKS, 64, 0, stream>>>(x, gate_w, probs, counts, toklist, wtslist);
  cleanup_kernel<<<1, 256, 0, stream>>>(probs, wtslist, counts, offsv, out + (size_t)TOKS * DIMD);
  // shared expert: U = silu(x@sw1^T)*(x@sw3^T)
  moe_gemm<0><<<dim3(HSH / 128, TOKS / 128), 256, 0, stream>>>(
      x, nullptr, sw1, sw3, U, nullptr, nullptr, nullptr, nullptr, nullptr);
  // y = U @ sw2^T  (initializes d_out)
  moe_gemm<1><<<dim3(DIMD / 128, TOKS / 128), 256, 0, stream>>>(
      nullptr, U, sw2, nullptr, nullptr, out, nullptr, nullptr, nullptr, nullptr);
  // routed: Act = silu(Xe@w1^T)*(Xe@w3^T)*wt
  moe_gemm<2><<<dim3(HE / 128, TOKS / 128, NE), 256, 0, stream>>>(
      x, nullptr, w1, w3, Act, nullptr, counts, offsv, toklist, wtslist);
  // y += Act @ w2^T (scatter)
  moe_gemm<3><<<dim3(DIMD / 128, TOKS / 128, NE), 256, 0, stream>>>(
      nullptr, Act, w2, nullptr, nullptr, out, counts, offsv, toklist, wtslist);
}

// Round 2
// 1200.997 us; speedup vs baseline: 1.4775x; 1.4775x over previous
//
#include <hip/hip_runtime.h>
#include <cstdint>

#define TOKS 4096
#define DIMD 2048
#define NE   16
#define HE   1408
#define HSH  2816
#define SLOTS 8192

typedef unsigned short u16;
typedef __attribute__((ext_vector_type(8))) __bf16 bf16x8;
typedef __attribute__((ext_vector_type(4))) float  f32x4;

__device__ inline unsigned f2bf_pack(float a, float b) {
  unsigned ua = __builtin_bit_cast(unsigned, a);
  unsigned ub = __builtin_bit_cast(unsigned, b);
  ua = (ua + 0x7FFFu + ((ua >> 16) & 1u)) >> 16;
  ub = (ub + 0x7FFFu + ((ub >> 16) & 1u)) >> 16;
  return ua | (ub << 16);
}
__device__ inline u16 f2bf(float a) {
  unsigned ua = __builtin_bit_cast(unsigned, a);
  return (u16)((ua + 0x7FFFu + ((ua >> 16) & 1u)) >> 16);
}

__device__ inline void gload_lds16(const u16* g, u16* l) {
  __builtin_amdgcn_global_load_lds((const __attribute__((address_space(1))) void*)g,
                                   (__attribute__((address_space(3))) void*)l, 16, 0, 0);
}

// ---------------- gate ----------------
__global__ __launch_bounds__(64)
void gate_kernel(const float* __restrict__ x, const float* __restrict__ gw,
                 float* __restrict__ probs, int* __restrict__ counts,
                 int* __restrict__ toklist, float* __restrict__ wtslist)
{
  const int t = blockIdx.x;
  const int l = threadIdx.x;
  const float4* xr = (const float4*)(x + (size_t)t * DIMD);
  float4 xv[8];
#pragma unroll
  for (int j = 0; j < 8; ++j) xv[j] = xr[j * 64 + l];

  float sc[16];
#pragma unroll
  for (int e = 0; e < 16; ++e) {
    const float4* g = (const float4*)(gw + (size_t)e * DIMD);
    float s = 0.f;
#pragma unroll
    for (int j = 0; j < 8; ++j) {
      float4 gv = g[j * 64 + l];
      s += xv[j].x * gv.x + xv[j].y * gv.y + xv[j].z * gv.z + xv[j].w * gv.w;
    }
#pragma unroll
    for (int o = 32; o > 0; o >>= 1) s += __shfl_down(s, o);
    sc[e] = s;
  }
  if (l == 0) {
    float mx = sc[0];
#pragma unroll
    for (int e = 1; e < 16; ++e) mx = fmaxf(mx, sc[e]);
    float pe[16]; float sum = 0.f;
#pragma unroll
    for (int e = 0; e < 16; ++e) { pe[e] = __expf(sc[e] - mx); sum += pe[e]; }
    float inv = 1.f / sum;
    int b0 = -1, b1 = -1; float v0 = -1.f, v1 = -1.f;
#pragma unroll
    for (int e = 0; e < 16; ++e) {
      float p = pe[e] * inv;
      probs[t * 16 + e] = p;
      if (p > v0) { v1 = v0; b1 = b0; v0 = p; b0 = e; }
      else if (p > v1) { v1 = p; b1 = e; }
    }
    float wsum = v0 + v1 + 1e-9f;
    float w0 = v0 / wsum, w1 = v1 / wsum;
    int p0 = atomicAdd(&counts[b0], 1);
    toklist[b0 * TOKS + p0] = t; wtslist[b0 * TOKS + p0] = w0;
    int p1 = atomicAdd(&counts[b1], 1);
    toklist[b1 * TOKS + p1] = t; wtslist[b1 * TOKS + p1] = w1;
  }
}

// ------------- cleanup -------------
__global__ __launch_bounds__(256)
void cleanup_kernel(const float* __restrict__ probs, const float* __restrict__ wtslist,
                    const int* __restrict__ counts, int* __restrict__ offs,
                    float* __restrict__ out_aux)
{
  const int tid = threadIdx.x;
  float imp[16], ld[16];
#pragma unroll
  for (int e = 0; e < 16; ++e) { imp[e] = 0.f; ld[e] = 0.f; }
  for (int t = tid; t < TOKS; t += 256) {
#pragma unroll
    for (int e = 0; e < 16; ++e) imp[e] += probs[t * 16 + e];
  }
  __shared__ int scnt[16];
  if (tid < 16) scnt[tid] = counts[tid];
  __syncthreads();
#pragma unroll
  for (int e = 0; e < 16; ++e) {
    int c = scnt[e];
    for (int p = tid; p < c; p += 256) ld[e] += wtslist[e * TOKS + p];
  }
  __shared__ float simp[16], sld[16];
  if (tid < 16) { simp[tid] = 0.f; sld[tid] = 0.f; }
  __syncthreads();
#pragma unroll
  for (int e = 0; e < 16; ++e) { atomicAdd(&simp[e], imp[e]); atomicAdd(&sld[e], ld[e]); }
  __syncthreads();
  if (tid == 0) {
    int off = 0;
    for (int e = 0; e < 16; ++e) { offs[e] = off; off += scnt[e]; }
    float tot = 0.f;
    for (int e = 0; e < 16; ++e) tot += sld[e];
    float aux = 0.f;
    for (int e = 0; e < 16; ++e) aux += (simp[e] / (float)TOKS) * (sld[e] / (tot + 1e-9f));
    *out_aux = 16.f * aux;
  }
}

// ------------- fp32 -> bf16 convert -------------
__global__ __launch_bounds__(256)
void cvt_f32_bf16(const float4* __restrict__ src, uint2* __restrict__ dst, int n4)
{
  int i = blockIdx.x * 256 + threadIdx.x;
  int stride = gridDim.x * 256;
  for (; i < n4; i += stride) {
    float4 v = src[i];
    uint2 p; p.x = f2bf_pack(v.x, v.y); p.y = f2bf_pack(v.z, v.w);
    dst[i] = p;
  }
}

// ------------- gather routed tokens into dense bf16 rows -------------
__global__ __launch_bounds__(256)
void gather_kernel(const float* __restrict__ x, const int* __restrict__ counts,
                   const int* __restrict__ offs, const int* __restrict__ toklist,
                   u16* __restrict__ Xg)
{
  int e = blockIdx.y;
  int cnt = counts[e];
  int p0 = blockIdx.x * 4;
  if (p0 >= cnt) return;
  int sub = threadIdx.x >> 6;
  int l = threadIdx.x & 63;
  int p = p0 + sub;
  if (p >= cnt) return;
  int tok = toklist[e * TOKS + p];
  const float4* srcr = (const float4*)(x + (size_t)tok * DIMD);
  uint2* dstr = (uint2*)(Xg + (size_t)(offs[e] + p) * DIMD);
#pragma unroll
  for (int j = 0; j < 8; ++j) {
    float4 v = srcr[j * 64 + l];
    uint2 q; q.x = f2bf_pack(v.x, v.y); q.y = f2bf_pack(v.z, v.w);
    dstr[j * 64 + l] = q;
  }
}

// ------------- fast bf16 MFMA GEMM (C = A * B^T), 128x128 tile, BK=64 -------------
// global_load_lds staging, XOR-swizzled LDS (source-swizzled, rule #21)
// MODE 0: A=xbf, B=sw1b,sw3b -> U bf16 (silu fused)
// MODE 1: A=U,   B=sw2b      -> y f32
// MODE 2: A=Xg,  B=w1b,w3b   -> Act bf16 (silu*wt fused)
// MODE 3: A=Act, B=w2b       -> atomicAdd y
template<int MODE>
__global__ __launch_bounds__(256)
void moe_gemm_f(const u16* __restrict__ A, const u16* __restrict__ Bg1,
                const u16* __restrict__ Bg3, u16* __restrict__ Obf,
                float* __restrict__ Of,
                const int* __restrict__ counts, const int* __restrict__ offs,
                const int* __restrict__ toklist, const float* __restrict__ wts)
{
  constexpr int KD = (MODE == 0) ? DIMD : (MODE == 1) ? HSH : (MODE == 2) ? DIMD : HE;
  constexpr int ND = (MODE == 0) ? HSH : (MODE == 1) ? DIMD : (MODE == 2) ? HE : DIMD;
  constexpr bool DUAL = (MODE == 0 || MODE == 2);

  __shared__ u16 sA[128 * 64];
  __shared__ u16 sB1[128 * 64];
  __shared__ u16 sB3[DUAL ? 128 * 64 : 16];

  const int tid  = threadIdx.x;
  const int lane = tid & 63;
  const int wave = tid >> 6;          // 0..3
  const int wm = wave >> 1, wn = wave & 1;
  const int mbase = blockIdx.y * 128;
  const int nbase = blockIdx.x * 128;

  int e = 0, cnt = 0;
  int arow0 = mbase;
  const u16* B1 = Bg1;
  const u16* B3 = Bg3;
  if constexpr (MODE == 2 || MODE == 3) {
    e = blockIdx.z; cnt = counts[e];
    if (mbase >= cnt) return;
    arow0 = offs[e] + mbase;
    B1 = Bg1 + (size_t)e * ND * KD;
    if constexpr (MODE == 2) B3 = Bg3 + (size_t)e * ND * KD;
  }

  f32x4 acc1[4][4];
  f32x4 acc3[DUAL ? 4 : 1][DUAL ? 4 : 1];
#pragma unroll
  for (int i = 0; i < 4; ++i)
#pragma unroll
    for (int j = 0; j < 4; ++j) {
      acc1[i][j] = (f32x4){0.f, 0.f, 0.f, 0.f};
      if constexpr (DUAL) acc3[i][j] = (f32x4){0.f, 0.f, 0.f, 0.f};
    }

  // staging: tile = 16 chunks of 8 rows; wave handles chunks wave*4..wave*4+3
  const int srow  = lane >> 3;                 // row within chunk
  const int sslot = (lane & 7) ^ srow;         // inverse-swizzled source slot
  const int scol  = sslot * 8;                 // u16 col offset within 64-col tile

  for (int kb = 0; kb < KD; kb += 64) {
#pragma unroll
    for (int i = 0; i < 4; ++i) {
      int c = wave * 4 + i;
      int row = c * 8 + srow;
      gload_lds16(A  + (size_t)(arow0 + row) * KD + kb + scol, &sA[c * 512]);
      gload_lds16(B1 + (size_t)(nbase + row) * KD + kb + scol, &sB1[c * 512]);
      if constexpr (DUAL)
        gload_lds16(B3 + (size_t)(nbase + row) * KD + kb + scol, &sB3[c * 512]);
    }
    __syncthreads();   // drains vmcnt(0): LDS tiles ready

#pragma unroll
    for (int ks = 0; ks < 2; ++ks) {
      bf16x8 a[4], b1f[4];
#pragma unroll
      for (int mi = 0; mi < 4; ++mi) {
        int r = wm * 64 + mi * 16 + (lane & 15);
        int s = (ks * 4 + (lane >> 4)) ^ (r & 7);
        a[mi] = *(const bf16x8*)((const char*)sA + r * 128 + s * 16);
      }
#pragma unroll
      for (int ni = 0; ni < 4; ++ni) {
        int r = wn * 64 + ni * 16 + (lane & 15);
        int s = (ks * 4 + (lane >> 4)) ^ (r & 7);
        b1f[ni] = *(const bf16x8*)((const char*)sB1 + r * 128 + s * 16);
      }
#pragma unroll
      for (int mi = 0; mi < 4; ++mi)
#pragma unroll
        for (int ni = 0; ni < 4; ++ni)
          acc1[mi][ni] = __builtin_amdgcn_mfma_f32_16x16x32_bf16(a[mi], b1f[ni], acc1[mi][ni], 0, 0, 0);
      if constexpr (DUAL) {
        bf16x8 b3f[4];
#pragma unroll
        for (int ni = 0; ni < 4; ++ni) {
          int r = wn * 64 + ni * 16 + (lane & 15);
          int s = (ks * 4 + (lane >> 4)) ^ (r & 7);
          b3f[ni] = *(const bf16x8*)((const char*)sB3 + r * 128 + s * 16);
        }
#pragma unroll
        for (int mi = 0; mi < 4; ++mi)
#pragma unroll
          for (int ni = 0; ni < 4; ++ni)
            acc3[mi][ni] = __builtin_amdgcn_mfma_f32_16x16x32_bf16(a[mi], b3f[ni], acc3[mi][ni], 0, 0, 0);
      }
    }
    __syncthreads();   // tiles consumed; safe to overwrite
  }

  // epilogue
  const int lr4 = (lane >> 4) * 4;
  const int lc  = lane & 15;
#pragma unroll
  for (int mi = 0; mi < 4; ++mi) {
#pragma unroll
    for (int ni = 0; ni < 4; ++ni) {
#pragma unroll
      for (int r = 0; r < 4; ++r) {
        int lrow = wm * 64 + mi * 16 + lr4 + r;
        int col  = nbase + wn * 64 + ni * 16 + lc;
        float v1 = acc1[mi][ni][r];
        if constexpr (MODE == 0) {
          float v3 = acc3[mi][ni][r];
          float u = (v1 / (1.f + __expf(-v1))) * v3;
          Obf[(size_t)(mbase + lrow) * ND + col] = f2bf(u);
        } else if constexpr (MODE == 1) {
          Of[(size_t)(mbase + lrow) * ND + col] = v1;
        } else if constexpr (MODE == 2) {
          int grow = mbase + lrow;
          if (grow < cnt) {
            float v3 = acc3[mi][ni][r];
            float u = (v1 / (1.f + __expf(-v1))) * v3 * wts[e * TOKS + grow];
            Obf[(size_t)(arow0 + lrow) * ND + col] = f2bf(u);
          }
        } else {
          int grow = mbase + lrow;
          if (grow < cnt) {
            int tok = toklist[e * TOKS + grow];
            atomicAdd(&Of[(size_t)tok * DIMD + col], v1);
          }
        }
      }
    }
  }
}

// ================= fallback slow path (round-1, known-good) =================
template<int MODE>
__global__ __launch_bounds__(256)
void moe_gemm_s(const float* __restrict__ Af, const u16* __restrict__ Ab,
                const float* __restrict__ B1g, const float* __restrict__ B3g,
                u16* __restrict__ Obf, float* __restrict__ Of,
                const int* __restrict__ counts, const int* __restrict__ offs,
                const int* __restrict__ toklist, const float* __restrict__ wts)
{
  constexpr int KD = (MODE == 0) ? DIMD : (MODE == 1) ? HSH : (MODE == 2) ? DIMD : HE;
  constexpr int ND = (MODE == 0) ? HSH : (MODE == 1) ? DIMD : (MODE == 2) ? HE : DIMD;
  constexpr bool DUAL = (MODE == 0 || MODE == 2);
  constexpr int LDP = 40;

  __shared__ u16 sA[128 * LDP];
  __shared__ u16 sB1[128 * LDP];
  __shared__ u16 sB3[DUAL ? 128 * LDP : 8];

  const int tid = threadIdx.x;
  const int lane = tid & 63;
  const int wave = tid >> 6;
  const int wm = wave >> 1, wn = wave & 1;
  const int mbase = blockIdx.y * 128;
  const int nbase = blockIdx.x * 128;

  int e = 0, cnt = 0;
  const int* tl = nullptr;
  long aoff = 0;
  const float* B1 = B1g;
  const float* B3 = B3g;
  if constexpr (MODE == 2) {
    e = blockIdx.z; cnt = counts[e];
    if (mbase >= cnt) return;
    tl = toklist + e * TOKS + mbase;
    B1 = B1g + (long)e * HE * DIMD;
    B3 = B3g + (long)e * HE * DIMD;
    aoff = offs[e];
  }
  if constexpr (MODE == 3) {
    e = blockIdx.z; cnt = counts[e];
    if (mbase >= cnt) return;
    tl = toklist + e * TOKS + mbase;
    B1 = B1g + (long)e * DIMD * HE;
    aoff = offs[e];
  }

  f32x4 acc1[4][4];
  f32x4 acc3[DUAL ? 4 : 1][DUAL ? 4 : 1];
#pragma unroll
  for (int i = 0; i < 4; ++i)
#pragma unroll
    for (int j = 0; j < 4; ++j) {
      acc1[i][j] = (f32x4){0.f, 0.f, 0.f, 0.f};
      if constexpr (DUAL) acc3[i][j] = (f32x4){0.f, 0.f, 0.f, 0.f};
    }

  int aoffs[4], boffs[4];
#pragma unroll
  for (int i = 0; i < 4; ++i) {
    aoffs[i] = (wm * 64 + i * 16 + (lane & 15)) * LDP + (lane >> 4) * 8;
    boffs[i] = (wn * 64 + i * 16 + (lane & 15)) * LDP + (lane >> 4) * 8;
  }

  for (int kb = 0; kb < KD; kb += 32) {
#pragma unroll
    for (int p = 0; p < 4; ++p) {
      int idx = tid + p * 256;
      int row = idx >> 3;
      int c4 = (idx & 7) * 4;
      if constexpr (MODE == 0) {
        float4 v = *(const float4*)(Af + (size_t)(mbase + row) * KD + kb + c4);
        uint2 pk; pk.x = f2bf_pack(v.x, v.y); pk.y = f2bf_pack(v.z, v.w);
        *(uint2*)&sA[row * LDP + c4] = pk;
      } else if constexpr (MODE == 2) {
        int r = mbase + row;
        int tok = (r < cnt) ? tl[row] : 0;
        float4 v = *(const float4*)(Af + (size_t)tok * DIMD + kb + c4);
        uint2 pk; pk.x = f2bf_pack(v.x, v.y); pk.y = f2bf_pack(v.z, v.w);
        *(uint2*)&sA[row * LDP + c4] = pk;
      } else {
        long arow;
        if constexpr (MODE == 1) arow = mbase + row;
        else arow = aoff + ((mbase + row < cnt) ? (mbase + row) : 0);
        uint2 v = *(const uint2*)(Ab + arow * KD + kb + c4);
        *(uint2*)&sA[row * LDP + c4] = v;
      }
      {
        float4 v = *(const float4*)(B1 + (size_t)(nbase + row) * KD + kb + c4);
        uint2 pk; pk.x = f2bf_pack(v.x, v.y); pk.y = f2bf_pack(v.z, v.w);
        *(uint2*)&sB1[row * LDP + c4] = pk;
      }
      if constexpr (DUAL) {
        float4 v = *(const float4*)(B3 + (size_t)(nbase + row) * KD + kb + c4);
        uint2 pk; pk.x = f2bf_pack(v.x, v.y); pk.y = f2bf_pack(v.z, v.w);
        *(uint2*)&sB3[row * LDP + c4] = pk;
      }
    }
    __syncthreads();
    bf16x8 af[4], b1f[4];
#pragma unroll
    for (int i = 0; i < 4; ++i) af[i] = *(const bf16x8*)&sA[aoffs[i]];
#pragma unroll
    for (int i = 0; i < 4; ++i) b1f[i] = *(const bf16x8*)&sB1[boffs[i]];
#pragma unroll
    for (int mi = 0; mi < 4; ++mi)
#pragma unroll
      for (int ni = 0; ni < 4; ++ni)
        acc1[mi][ni] = __builtin_amdgcn_mfma_f32_16x16x32_bf16(af[mi], b1f[ni], acc1[mi][ni], 0, 0, 0);
    if constexpr (DUAL) {
      bf16x8 b3f[4];
#pragma unroll
      for (int i = 0; i < 4; ++i) b3f[i] = *(const bf16x8*)&sB3[boffs[i]];
#pragma unroll
      for (int mi = 0; mi < 4; ++mi)
#pragma unroll
        for (int ni = 0; ni < 4; ++ni)
          acc3[mi][ni] = __builtin_amdgcn_mfma_f32_16x16x32_bf16(af[mi], b3f[ni], acc3[mi][ni], 0, 0, 0);
    }
    __syncthreads();
  }

  const int lq4 = (lane >> 4) * 4;
  const int lc = lane & 15;
#pragma unroll
  for (int mi = 0; mi < 4; ++mi) {
#pragma unroll
    for (int ni = 0; ni < 4; ++ni) {
#pragma unroll
      for (int r = 0; r < 4; ++r) {
        int lrow = wm * 64 + mi * 16 + lq4 + r;
        int col = nbase + wn * 64 + ni * 16 + lc;
        float v1 = acc1[mi][ni][r];
        if constexpr (MODE == 0) {
          float v3 = acc3[mi][ni][r];
          float u = (v1 / (1.f + __expf(-v1))) * v3;
          Obf[(size_t)(mbase + lrow) * ND + col] = f2bf(u);
        } else if constexpr (MODE == 1) {
          Of[(size_t)(mbase + lrow) * ND + col] = v1;
        } else if constexpr (MODE == 2) {
          int grow = mbase + lrow;
          if (grow < cnt) {
            float v3 = acc3[mi][ni][r];
            float u = (v1 / (1.f + __expf(-v1))) * v3 * wts[e * TOKS + grow];
            Obf[(size_t)(aoff + grow) * ND + col] = f2bf(u);
          }
        } else {
          int grow = mbase + lrow;
          if (grow < cnt) {
            int tok = toklist[e * TOKS + grow];
            atomicAdd(&Of[(size_t)tok * DIMD + col], v1);
          }
        }
      }
    }
  }
}

extern "C" void kernel_launch(void* const* d_in, const int* in_sizes, int n_in,
                              void* d_out, int out_size, void* d_ws, size_t ws_size,
                              hipStream_t stream) {
  const float* x      = (const float*)d_in[0];
  const float* gate_w = (const float*)d_in[1];
  const float* w1     = (const float*)d_in[2];
  const float* w2     = (const float*)d_in[3];
  const float* w3     = (const float*)d_in[4];
  const float* sw1    = (const float*)d_in[5];
  const float* sw2    = (const float*)d_in[6];
  const float* sw3    = (const float*)d_in[7];
  float* out = (float*)d_out;

  char* ws = (char*)d_ws;
  int*   counts  = (int*)ws;
  int*   offsv   = (int*)(ws + 256);
  int*   toklist = (int*)(ws + 512);
  float* wtslist = (float*)(ws + 262656);
  float* probs   = (float*)(ws + 524800);

  size_t o = 1 << 20;
  u16* xbf  = (u16*)(ws + o); o += (size_t)TOKS * DIMD * 2;
  u16* Xg   = (u16*)(ws + o); o += (size_t)(SLOTS + 128) * DIMD * 2;
  u16* w1b  = (u16*)(ws + o); o += (size_t)NE * HE * DIMD * 2;
  u16* w3b  = (u16*)(ws + o); o += (size_t)NE * HE * DIMD * 2;
  u16* w2b  = (u16*)(ws + o); o += (size_t)NE * DIMD * HE * 2;
  u16* sw1b = (u16*)(ws + o); o += (size_t)HSH * DIMD * 2;
  u16* sw3b = (u16*)(ws + o); o += (size_t)HSH * DIMD * 2;
  u16* sw2b = (u16*)(ws + o); o += (size_t)DIMD * HSH * 2;
  u16* U    = (u16*)(ws + o); o += (size_t)TOKS * HSH * 2;
  u16* Act  = (u16*)(ws + o); o += (size_t)(SLOTS + 128) * HE * 2;
  const bool fast = (ws_size >= o);

  hipMemsetAsync(counts, 0, 64, stream);
  gate_kernel<<<TOKS, 64, 0, stream>>>(x, gate_w, probs, counts, toklist, wtslist);
  cleanup_kernel<<<1, 256, 0, stream>>>(probs, wtslist, counts, offsv, out + (size_t)TOKS * DIMD);

  if (fast) {
    cvt_f32_bf16<<<2048, 256, 0, stream>>>((const float4*)x,   (uint2*)xbf,  TOKS * DIMD / 4);
    cvt_f32_bf16<<<4096, 256, 0, stream>>>((const float4*)w1,  (uint2*)w1b,  NE * HE * DIMD / 4);
    cvt_f32_bf16<<<4096, 256, 0, stream>>>((const float4*)w3,  (uint2*)w3b,  NE * HE * DIMD / 4);
    cvt_f32_bf16<<<4096, 256, 0, stream>>>((const float4*)w2,  (uint2*)w2b,  NE * DIMD * HE / 4);
    cvt_f32_bf16<<<2048, 256, 0, stream>>>((const float4*)sw1, (uint2*)sw1b, HSH * DIMD / 4);
    cvt_f32_bf16<<<2048, 256, 0, stream>>>((const float4*)sw3, (uint2*)sw3b, HSH * DIMD / 4);
    cvt_f32_bf16<<<2048, 256, 0, stream>>>((const float4*)sw2, (uint2*)sw2b, DIMD * HSH / 4);
    gather_kernel<<<dim3(TOKS / 4, NE), 256, 0, stream>>>(x, counts, offsv, toklist, Xg);

    moe_gemm_f<0><<<dim3(HSH / 128, TOKS / 128), 256, 0, stream>>>(
        xbf, sw1b, sw3b, U, nullptr, nullptr, nullptr, nullptr, nullptr);
    moe_gemm_f<1><<<dim3(DIMD / 128, TOKS / 128), 256, 0, stream>>>(
        U, sw2b, nullptr, nullptr, out, nullptr, nullptr, nullptr, nullptr);
    moe_gemm_f<2><<<dim3(HE / 128, TOKS / 128, NE), 256, 0, stream>>>(
        Xg, w1b, w3b, Act, nullptr, counts, offsv, toklist, wtslist);
    moe_gemm_f<3><<<dim3(DIMD / 128, TOKS / 128, NE), 256, 0, stream>>>(
        Act, w2b, nullptr, nullptr, out, counts, offsv, toklist, wtslist);
  } else {
    u16* U_s   = (u16*)(ws + (1 << 20));
    u16* Act_s = (u16*)(ws + (1 << 20) + (size_t)TOKS * HSH * 2);
    moe_gemm_s<0><<<dim3(HSH / 128, TOKS / 128), 256, 0, stream>>>(
        x, nullptr, sw1, sw3, U_s, nullptr, nullptr, nullptr, nullptr, nullptr);
    moe_gemm_s<1><<<dim3(DIMD / 128, TOKS / 128), 256, 0, stream>>>(
        nullptr, U_s, sw2, nullptr, nullptr, out, nullptr, nullptr, nullptr, nullptr);
    moe_gemm_s<2><<<dim3(HE / 128, TOKS / 128, NE), 256, 0, stream>>>(
        x, nullptr, w1, w3, Act_s, nullptr, counts, offsv, toklist, wtslist);
    moe_gemm_s<3><<<dim3(DIMD / 128, TOKS / 128, NE), 256, 0, stream>>>(
        nullptr, Act_s, w2, nullptr, nullptr, out, counts, offsv, toklist, wtslist);
  }
}